// Round 1
// baseline (186.978 us; speedup 1.0000x reference)
//
#include <hip/hip_runtime.h>
#include <hip/hip_bf16.h>
#include <math.h>

#define BATCH 16384
#define EMBED 128
#define NPOS 10
#define NNEG 50

// Stable log-sigmoid: log(1/(1+e^-x)) = min(x,0) - log1p(exp(-|x|))
__device__ __forceinline__ float log_sigmoid(float x) {
    return fminf(x, 0.0f) - log1pf(__expf(-fabsf(x)));
}

__global__ __launch_bounds__(256) void skipgram_loss_kernel(
    const int* __restrict__ input_labels,   // [B]
    const int* __restrict__ pos_labels,     // [B, P]
    const int* __restrict__ neg_labels,     // [B, N]
    const float* __restrict__ in_embed,     // [V, D]
    const float* __restrict__ out_embed,    // [V, D]
    float* __restrict__ out)                // [B]
{
    const int wave = threadIdx.x >> 6;          // 0..3
    const int lane = threadIdx.x & 63;
    const int b = blockIdx.x * 4 + wave;
    if (b >= BATCH) return;

    // Center row: lane i holds elements [2i, 2i+1]  (8 B/lane, 512 B/wave, coalesced)
    const int ci = input_labels[b];
    const float2 c = *reinterpret_cast<const float2*>(
        &in_embed[(size_t)ci * EMBED + lane * 2]);

    float log_pos = 0.0f;
    #pragma unroll
    for (int p = 0; p < NPOS; ++p) {
        const int l = pos_labels[b * NPOS + p];
        const float2 r = *reinterpret_cast<const float2*>(
            &out_embed[(size_t)l * EMBED + lane * 2]);
        float part = c.x * r.x + c.y * r.y;
        #pragma unroll
        for (int off = 32; off; off >>= 1) part += __shfl_xor(part, off);
        log_pos += log_sigmoid(part);
    }

    float log_neg = 0.0f;
    #pragma unroll
    for (int n = 0; n < NNEG; ++n) {
        const int l = neg_labels[b * NNEG + n];
        const float2 r = *reinterpret_cast<const float2*>(
            &out_embed[(size_t)l * EMBED + lane * 2]);
        float part = c.x * r.x + c.y * r.y;
        #pragma unroll
        for (int off = 32; off; off >>= 1) part += __shfl_xor(part, off);
        log_neg += log_sigmoid(part);
    }

    // reference returns -loss = -(log_pos - log_neg) = log_neg - log_pos
    if (lane == 0) out[b] = log_neg - log_pos;
}

extern "C" void kernel_launch(void* const* d_in, const int* in_sizes, int n_in,
                              void* d_out, int out_size, void* d_ws, size_t ws_size,
                              hipStream_t stream) {
    const int*   input_labels = (const int*)d_in[0];
    const int*   pos_labels   = (const int*)d_in[1];
    const int*   neg_labels   = (const int*)d_in[2];
    const float* in_embed     = (const float*)d_in[3];
    const float* out_embed    = (const float*)d_in[4];
    float*       out          = (float*)d_out;

    // 4 waves (4 batch elements) per 256-thread block
    const int blocks = BATCH / 4;  // 4096
    skipgram_loss_kernel<<<blocks, 256, 0, stream>>>(
        input_labels, pos_labels, neg_labels, in_embed, out_embed, out);
}

// Round 2
// 118.388 us; speedup vs baseline: 1.5794x; 1.5794x over previous
//
#include <hip/hip_runtime.h>
#include <hip/hip_bf16.h>
#include <math.h>

#define BATCH 16384
#define EMBED 128
#define NPOS 10
#define NNEG 50

// Stable log-sigmoid: log(1/(1+e^-x)) = min(x,0) - log1p(exp(-|x|))
__device__ __forceinline__ float log_sigmoid(float x) {
    return fminf(x, 0.0f) - log1pf(__expf(-fabsf(x)));
}

__global__ __launch_bounds__(256) void skipgram_loss_kernel(
    const int* __restrict__ input_labels,   // [B]
    const int* __restrict__ pos_labels,     // [B, P]
    const int* __restrict__ neg_labels,     // [B, N]
    const float* __restrict__ in_embed,     // [V, D]
    const float* __restrict__ out_embed,    // [V, D]
    float* __restrict__ out)                // [B]
{
    const int wave = threadIdx.x >> 6;          // 0..3
    const int lane = threadIdx.x & 63;
    const int b = blockIdx.x * 4 + wave;

    // Center row base (wave-uniform -> scalar/broadcast loads)
    const int ci = input_labels[b];
    const float* __restrict__ crow = in_embed + (size_t)ci * EMBED;

    // One lane per label: lanes 0..9 pos (w=-1), 10..59 neg (w=+1), 60..63 idle (w=0)
    int label;
    float w;
    if (lane < NPOS) {
        label = pos_labels[b * NPOS + lane];
        w = -1.0f;
    } else if (lane < NPOS + NNEG) {
        label = neg_labels[b * NNEG + (lane - NPOS)];
        w = 1.0f;
    } else {
        label = 0;
        w = 0.0f;
    }
    const float* __restrict__ rrow = out_embed + (size_t)label * EMBED;

    // Private 128-length dot product, 4 accumulators for ILP
    float a0 = 0.f, a1 = 0.f, a2 = 0.f, a3 = 0.f;
    #pragma unroll
    for (int d = 0; d < EMBED; d += 4) {
        const float4 cv = *reinterpret_cast<const float4*>(crow + d);
        const float4 rv = *reinterpret_cast<const float4*>(rrow + d);
        a0 = fmaf(cv.x, rv.x, a0);
        a1 = fmaf(cv.y, rv.y, a1);
        a2 = fmaf(cv.z, rv.z, a2);
        a3 = fmaf(cv.w, rv.w, a3);
    }
    const float dot = (a0 + a1) + (a2 + a3);

    // Signed log-sigmoid; single butterfly sum produces log_neg - log_pos
    float s = w * log_sigmoid(dot);
    #pragma unroll
    for (int off = 32; off; off >>= 1) s += __shfl_xor(s, off);

    if (lane == 0) out[b] = s;
}

extern "C" void kernel_launch(void* const* d_in, const int* in_sizes, int n_in,
                              void* d_out, int out_size, void* d_ws, size_t ws_size,
                              hipStream_t stream) {
    const int*   input_labels = (const int*)d_in[0];
    const int*   pos_labels   = (const int*)d_in[1];
    const int*   neg_labels   = (const int*)d_in[2];
    const float* in_embed     = (const float*)d_in[3];
    const float* out_embed    = (const float*)d_in[4];
    float*       out          = (float*)d_out;

    const int blocks = BATCH / 4;  // 4096 blocks x 256 threads = 4 batch elems/block
    skipgram_loss_kernel<<<blocks, 256, 0, stream>>>(
        input_labels, pos_labels, neg_labels, in_embed, out_embed, out);
}

// Round 3
// 72.162 us; speedup vs baseline: 2.5911x; 1.6406x over previous
//
#include <hip/hip_runtime.h>
#include <hip/hip_bf16.h>
#include <math.h>

#define BATCH 16384
#define EMBED 128
#define NPOS 10
#define NNEG 50
#define NLAB (NPOS + NNEG)   // 60

// Stable log-sigmoid: log(1/(1+e^-x)) = min(x,0) - log1p(exp(-|x|))
__device__ __forceinline__ float log_sigmoid(float x) {
    return fminf(x, 0.0f) - log1pf(__expf(-fabsf(x)));
}

__device__ __forceinline__ float dot4(float4 a, float4 b) {
    return fmaf(a.x, b.x, fmaf(a.y, b.y, fmaf(a.z, b.z, a.w * b.w)));
}

__global__ __launch_bounds__(256) void skipgram_loss_kernel(
    const int* __restrict__ input_labels,   // [B]
    const int* __restrict__ pos_labels,     // [B, P]
    const int* __restrict__ neg_labels,     // [B, N]
    const float* __restrict__ in_embed,     // [V, D]
    const float* __restrict__ out_embed,    // [V, D]
    float* __restrict__ out)                // [B]
{
    const int wave = threadIdx.x >> 6;          // 0..3
    const int lane = threadIdx.x & 63;
    const int b = blockIdx.x * 4 + wave;
    const int g = lane >> 3;                    // label group 0..7
    const int t = lane & 7;                     // slot within group

    // Center row (wave-uniform address). Lane covers elements j*32 + t*4 .. +3.
    const int ci = input_labels[b];
    const float* __restrict__ crow = in_embed + (size_t)ci * EMBED;
    const float4 c0 = *reinterpret_cast<const float4*>(crow + 0 * 32 + t * 4);
    const float4 c1 = *reinterpret_cast<const float4*>(crow + 1 * 32 + t * 4);
    const float4 c2 = *reinterpret_cast<const float4*>(crow + 2 * 32 + t * 4);
    const float4 c3 = *reinterpret_cast<const float4*>(crow + 3 * 32 + t * 4);

    // Preload one label per lane (slot li == lane); slots 60..63 idle.
    int lab;
    if (lane < NPOS)       lab = pos_labels[b * NPOS + lane];
    else if (lane < NLAB)  lab = neg_labels[b * NNEG + (lane - NPOS)];
    else                   lab = 0;

    float total = 0.0f;
    #pragma unroll
    for (int p = 0; p < 8; ++p) {
        const int li = p * 8 + g;                       // this group's label slot
        const int l  = __shfl(lab, li);                 // broadcast label
        const float wl = (li < NLAB) ? ((li < NPOS) ? -1.0f : 1.0f) : 0.0f;

        const float* __restrict__ rrow = out_embed + (size_t)l * EMBED;
        // Within a group, the 8 lanes' float4s are contiguous: 128 B/group/instr.
        const float4 r0 = *reinterpret_cast<const float4*>(rrow + 0 * 32 + t * 4);
        const float4 r1 = *reinterpret_cast<const float4*>(rrow + 1 * 32 + t * 4);
        const float4 r2 = *reinterpret_cast<const float4*>(rrow + 2 * 32 + t * 4);
        const float4 r3 = *reinterpret_cast<const float4*>(rrow + 3 * 32 + t * 4);

        float acc = dot4(c0, r0) + dot4(c1, r1) + dot4(c2, r2) + dot4(c3, r3);

        // In-group butterfly (lanes differ only in bits 0..2)
        acc += __shfl_xor(acc, 1);
        acc += __shfl_xor(acc, 2);
        acc += __shfl_xor(acc, 4);

        // Only slot-0 lane of each group accumulates the signed log-sigmoid
        total += (t == 0) ? wl * log_sigmoid(acc) : 0.0f;
    }

    // Cross-group reduction (non-t0 lanes carry 0)
    total += __shfl_xor(total, 8);
    total += __shfl_xor(total, 16);
    total += __shfl_xor(total, 32);

    if (lane == 0) out[b] = total;   // = log_neg - log_pos = -loss
}

extern "C" void kernel_launch(void* const* d_in, const int* in_sizes, int n_in,
                              void* d_out, int out_size, void* d_ws, size_t ws_size,
                              hipStream_t stream) {
    const int*   input_labels = (const int*)d_in[0];
    const int*   pos_labels   = (const int*)d_in[1];
    const int*   neg_labels   = (const int*)d_in[2];
    const float* in_embed     = (const float*)d_in[3];
    const float* out_embed    = (const float*)d_in[4];
    float*       out          = (float*)d_out;

    const int blocks = BATCH / 4;  // 4096 blocks x 256 threads = 4 batch elems/block
    skipgram_loss_kernel<<<blocks, 256, 0, stream>>>(
        input_labels, pos_labels, neg_labels, in_embed, out_embed, out);
}